// Round 3
// baseline (11255.679 us; speedup 1.0000x reference)
//
#include <hip/hip_runtime.h>

typedef unsigned short u16;
typedef unsigned int   u32;
typedef unsigned long long u64;
typedef __attribute__((ext_vector_type(8))) short  bf16x8;
typedef __attribute__((ext_vector_type(4))) float  f32x4;

#define B_   128
#define T_   1024
#define I_   64
#define H_   512
#define G4_  2048

#define NG_   8     // batch groups
#define BGRP_ 16    // batch rows per group
#define NBH_  16    // h-chunk blocks per group per layer
#define HC_   32    // h columns per chunk block
#define GC_   128   // gate columns per chunk block (4*HC_)
#define R_    4     // inter-layer ring depth (power of 2)

__device__ __forceinline__ float b2f(u16 u){ return __uint_as_float(((u32)u)<<16); }
__device__ __forceinline__ u16  f2b(float f){ u32 u = __float_as_uint(f); return (u16)((u + 0x7fffu + ((u>>16)&1u))>>16); }
__device__ __forceinline__ float sigf(float x){ return 1.f/(1.f + __expf(-x)); }
__device__ __forceinline__ float tanh_f(float x){
    float a = fabsf(x); float e = __expf(-2.f*a);
    float r = (1.f-e)/(1.f+e); return x<0.f ? -r : r;
}
// XOR swizzle for 1024-byte LDS rows (2-way max on ds_read_b128 = free)
__device__ __forceinline__ int swz(int row, int colbyte){ return row*1024 + (colbyte ^ ((row&7)<<4)); }

// load 8 consecutive fp32 -> bf16x8 fragment (16B-aligned source)
__device__ __forceinline__ bf16x8 ld8f(const float* p){
    float4 a = *(const float4*)p, b = *(const float4*)(p+4);
    bf16x8 r;
    r[0]=(short)f2b(a.x); r[1]=(short)f2b(a.y); r[2]=(short)f2b(a.z); r[3]=(short)f2b(a.w);
    r[4]=(short)f2b(b.x); r[5]=(short)f2b(b.y); r[6]=(short)f2b(b.z); r[7]=(short)f2b(b.w);
    return r;
}

#define MFMA(a,b,c) __builtin_amdgcn_mfma_f32_16x16x32_bf16((a),(b),(c),0,0,0)

static constexpr int N_FLG = 2*NG_*NBH_;   // 256 flags

// ---------------- h_init = (cond @ Wc^T + bc) @ Wi^T + bi ; also zero flags ----------------
__global__ void k_prep(const float* __restrict__ cond, const float* __restrict__ Wc,
                       const float* __restrict__ bc,   const float* __restrict__ Wi,
                       const float* __restrict__ bi,   u16* ring, u16* h1buf, u32* flg)
{
    __shared__ float cp[32];
    int b = blockIdx.x, tid = threadIdx.x;
    if (b == 0 && tid < N_FLG) flg[tid] = 0u;
    if (tid < 32) {
        float s = bc[tid];
        #pragma unroll
        for (int i=0;i<10;++i) s += cond[b*10+i]*Wc[tid*10+i];
        cp[tid] = s;
    }
    __syncthreads();
    float s = bi[tid];
    #pragma unroll
    for (int c=0;c<32;++c) s += cp[c]*Wi[tid*32+c];
    u16 hv = f2b(s);
    ring [((size_t)(R_-1)*B_ + b)*H_ + tid] = hv;  // layer-0 recurrent init (slot R-1)
    h1buf[(size_t)b*H_ + tid]              = hv;  // layer-1 recurrent init (buffer 0)
}

// ---------------- fused 2-layer pipelined LSTM ----------------
// 256 blocks, 1-D. grp = bid&7 (-> same XCD under round-robin dispatch),
// layer = (bid>>3)>>4, chunk = (bid>>3)&15. 1 block/CU, all co-resident.
__global__ __launch_bounds__(256, 1)
void k_fused(const float* __restrict__ x,
             const float* __restrict__ Wih0f, const float* __restrict__ Whh0f,
             const float* __restrict__ Wih1f, const float* __restrict__ Whh1f,
             const float* __restrict__ bih0f, const float* __restrict__ bhh0f,
             const float* __restrict__ bih1f, const float* __restrict__ bhh1f,
             u16* ring,     // [R_][B][512] bf16 (layer-0 h + its own recurrence)
             u16* h1buf,    // [2][B][512] bf16 (layer-1 recurrence)
             u32* flagbase, // [2][NG_][NBH_]
             float* hlast)  // [B][512] f32
{
    __shared__ u16  lds_a[BGRP_*H_];   // 16KB swizzled (L0: h0 prev; L1: h0[t] input)
    __shared__ u16  lds_b[BGRP_*H_];   // 16KB swizzled (L0: x tile (2KB used); L1: h1 prev)
    __shared__ float lds_g[BGRP_*GC_]; // 8KB gate staging

    const int tid = threadIdx.x;
    const int w = tid>>6, lane = tid&63;
    const int bid = blockIdx.x;
    const int grp = bid & 7;
    const int rest = bid >> 3;
    const int layer = rest >> 4, chunk = rest & 15;
    const int n0 = chunk*HC_;
    const int gb = grp*BGRP_;
    u32* f0 = flagbase + grp*NBH_;
    u32* f1 = flagbase + NG_*NBH_ + grp*NBH_;

    // combine mapping: thread -> (batch row prow, h-cols phc, phc+1)
    const int prow = tid>>4;
    const int phc  = (2*tid)&31;
    // staging mapping: thread -> (row srow, 8 u64 at sc8)
    const int srow = tid>>4, sc8 = (tid&15)*8;

    // biases in registers (bih+bhh, fp32)
    const float* ba = (layer==0) ? bih0f : bih1f;
    const float* bb = (layer==0) ? bhh0f : bhh1f;
    float bias[8];
    #pragma unroll
    for (int q=0;q<4;++q){
        int idx = q*H_ + n0 + phc;
        bias[2*q]   = ba[idx]   + bb[idx];
        bias[2*q+1] = ba[idx+1] + bb[idx+1];
    }

    float c0 = 0.f, c1 = 0.f;

    // B-fragment gate-row indices for this wave's two 16-col N-tiles
    const int s0i = 2*w*16 + (lane&15), s1i = s0i+16;
    const int r0 = (s0i>>5)*H_ + n0 + (s0i&31);   // weight row (gate-major)
    const int r1 = (s1i>>5)*H_ + n0 + (s1i&31);
    const int kc = (lane>>4)*8;                   // k offset within frag

    if (layer == 0) {
        // ---- preload Whh0 (16x2 frags) + Wih0 (2x2 frags), fp32->bf16 in-register ----
        bf16x8 bh0[16], bh1[16], bx0[2], bx1[2];
        {
            const float* p0 = Whh0f + (size_t)r0*H_ + kc;
            const float* p1 = Whh0f + (size_t)r1*H_ + kc;
            #pragma unroll
            for (int kt=0;kt<16;++kt){ bh0[kt]=ld8f(p0+kt*32); bh1[kt]=ld8f(p1+kt*32); }
            const float* q0 = Wih0f + (size_t)r0*I_ + kc;
            const float* q1 = Wih0f + (size_t)r1*I_ + kc;
            #pragma unroll
            for (int kt=0;kt<2;++kt){ bx0[kt]=ld8f(q0+kt*32); bx1[kt]=ld8f(q1+kt*32); }
        }

        for (int t = 0; t < T_; ++t) {
            // wait: own-layer step t-1 done everywhere; ring slot t%R free (L1 did t-R+1... = t-3)
            if (tid < 16) {
                while ((int)__hip_atomic_load(&f0[tid], __ATOMIC_ACQUIRE, __HIP_MEMORY_SCOPE_AGENT) < t)
                    __builtin_amdgcn_s_sleep(1);
            } else if (tid < 32) {
                int need = t - (R_-1);
                while ((int)__hip_atomic_load(&f1[tid-16], __ATOMIC_ACQUIRE, __HIP_MEMORY_SCOPE_AGENT) < need)
                    __builtin_amdgcn_s_sleep(1);
            }
            __syncthreads();

            // stage x[gb..gb+16][t][0..64) fp32 -> bf16, swizzled 128B rows in lds_b
            {
                const float* xp = x + ((size_t)(gb+srow)*T_ + t)*I_ + (tid&15)*4;
                float4 v = *(const float4*)xp;
                u16 a=f2b(v.x), b=f2b(v.y), c=f2b(v.z), d=f2b(v.w);
                u64 pk = (u64)((u32)a|((u32)b<<16)) | ((u64)((u32)c|((u32)d<<16))<<32);
                *(u64*)((char*)lds_b + srow*128 + (((tid&15)*8) ^ ((srow&7)<<4))) = pk;
            }
            // stage h0[t-1] from ring slot (t-1)%R (coherent u64 loads) into lds_a
            {
                const int ps = (t + R_ - 1) & (R_-1);
                const u64* src = (const u64*)(ring + ((size_t)ps*B_ + gb + srow)*H_) + sc8;
                #pragma unroll
                for (int i=0;i<8;++i){
                    u64 v = __hip_atomic_load(src+i, __ATOMIC_RELAXED, __HIP_MEMORY_SCOPE_AGENT);
                    *(u64*)((char*)lds_a + swz(srow, (sc8+i)*8)) = v;
                }
            }
            __syncthreads();

            // gates = x @ Wih0^T + h @ Whh0^T
            f32x4 acc0 = {0.f,0.f,0.f,0.f}, acc1 = {0.f,0.f,0.f,0.f};
            #pragma unroll
            for (int kt=0;kt<2;++kt){
                bf16x8 a = *(const bf16x8*)((char*)lds_b + (lane&15)*128 + ((kt*64 + (lane>>4)*16) ^ (((lane&15)&7)<<4)));
                acc0 = MFMA(a, bx0[kt], acc0);
                acc1 = MFMA(a, bx1[kt], acc1);
            }
            #pragma unroll
            for (int kt=0;kt<16;++kt){
                bf16x8 a = *(const bf16x8*)((char*)lds_a + swz(lane&15, kt*64 + (lane>>4)*16));
                acc0 = MFMA(a, bh0[kt], acc0);
                acc1 = MFMA(a, bh1[kt], acc1);
            }
            {
                int gr=(lane>>4)*4, gc=lane&15;
                #pragma unroll
                for (int j=0;j<4;++j){
                    lds_g[(gr+j)*GC_ + 2*w*16      + gc] = acc0[j];
                    lds_g[(gr+j)*GC_ + (2*w+1)*16  + gc] = acc1[j];
                }
            }
            __syncthreads();

            // combine -> h0[t] into ring slot t%R
            {
                float2 gi = *(const float2*)&lds_g[prow*GC_ +      phc];
                float2 gf = *(const float2*)&lds_g[prow*GC_ + 32 + phc];
                float2 gg = *(const float2*)&lds_g[prow*GC_ + 64 + phc];
                float2 go = *(const float2*)&lds_g[prow*GC_ + 96 + phc];
                c0 = sigf(gf.x+bias[2])*c0 + sigf(gi.x+bias[0])*tanh_f(gg.x+bias[4]);
                c1 = sigf(gf.y+bias[3])*c1 + sigf(gi.y+bias[1])*tanh_f(gg.y+bias[5]);
                float h0v = sigf(go.x+bias[6])*tanh_f(c0);
                float h1v = sigf(go.y+bias[7])*tanh_f(c1);
                u32 pack = (u32)f2b(h0v) | ((u32)f2b(h1v)<<16);
                const int cs = t & (R_-1);
                __hip_atomic_store((u32*)(ring + ((size_t)cs*B_ + gb + prow)*H_ + n0 + phc),
                                   pack, __ATOMIC_RELAXED, __HIP_MEMORY_SCOPE_AGENT);
            }
            __syncthreads();
            if (tid == 0)
                __hip_atomic_store(&f0[chunk], (u32)(t+1), __ATOMIC_RELEASE, __HIP_MEMORY_SCOPE_AGENT);
        }
    } else {
        // ---- preload Wih1 + Whh1 (16x2 frags each = 256 VGPR), fp32->bf16 in-register ----
        bf16x8 bi0[16], bi1[16], bh0[16], bh1[16];
        {
            const float* p0 = Wih1f + (size_t)r0*H_ + kc;
            const float* p1 = Wih1f + (size_t)r1*H_ + kc;
            const float* q0 = Whh1f + (size_t)r0*H_ + kc;
            const float* q1 = Whh1f + (size_t)r1*H_ + kc;
            #pragma unroll
            for (int kt=0;kt<16;++kt){
                bi0[kt]=ld8f(p0+kt*32); bi1[kt]=ld8f(p1+kt*32);
                bh0[kt]=ld8f(q0+kt*32); bh1[kt]=ld8f(q1+kt*32);
            }
        }

        for (int t = 0; t < T_; ++t) {
            // wait: own-layer step t-1 done everywhere; layer-0 finished step t
            if (tid < 16) {
                while ((int)__hip_atomic_load(&f1[tid], __ATOMIC_ACQUIRE, __HIP_MEMORY_SCOPE_AGENT) < t)
                    __builtin_amdgcn_s_sleep(1);
            } else if (tid < 32) {
                while ((int)__hip_atomic_load(&f0[tid-16], __ATOMIC_ACQUIRE, __HIP_MEMORY_SCOPE_AGENT) < t+1)
                    __builtin_amdgcn_s_sleep(1);
            }
            __syncthreads();

            // stage h0[t] (ring slot t%R) -> lds_a ; h1[t-1] (h1buf[t&1]) -> lds_b
            {
                const int cs = t & (R_-1);
                const u64* sa_ = (const u64*)(ring  + ((size_t)cs*B_    + gb + srow)*H_) + sc8;
                const u64* sb_ = (const u64*)(h1buf + ((size_t)(t&1)*B_ + gb + srow)*H_) + sc8;
                #pragma unroll
                for (int i=0;i<8;++i){
                    u64 v = __hip_atomic_load(sa_+i, __ATOMIC_RELAXED, __HIP_MEMORY_SCOPE_AGENT);
                    *(u64*)((char*)lds_a + swz(srow, (sc8+i)*8)) = v;
                }
                #pragma unroll
                for (int i=0;i<8;++i){
                    u64 v = __hip_atomic_load(sb_+i, __ATOMIC_RELAXED, __HIP_MEMORY_SCOPE_AGENT);
                    *(u64*)((char*)lds_b + swz(srow, (sc8+i)*8)) = v;
                }
            }
            __syncthreads();

            // gates = h0_in @ Wih1^T + h1_prev @ Whh1^T
            f32x4 acc0 = {0.f,0.f,0.f,0.f}, acc1 = {0.f,0.f,0.f,0.f};
            #pragma unroll
            for (int kt=0;kt<16;++kt){
                bf16x8 a0 = *(const bf16x8*)((char*)lds_a + swz(lane&15, kt*64 + (lane>>4)*16));
                bf16x8 a1 = *(const bf16x8*)((char*)lds_b + swz(lane&15, kt*64 + (lane>>4)*16));
                acc0 = MFMA(a0, bi0[kt], acc0);
                acc1 = MFMA(a0, bi1[kt], acc1);
                acc0 = MFMA(a1, bh0[kt], acc0);
                acc1 = MFMA(a1, bh1[kt], acc1);
            }
            {
                int gr=(lane>>4)*4, gc=lane&15;
                #pragma unroll
                for (int j=0;j<4;++j){
                    lds_g[(gr+j)*GC_ + 2*w*16      + gc] = acc0[j];
                    lds_g[(gr+j)*GC_ + (2*w+1)*16  + gc] = acc1[j];
                }
            }
            __syncthreads();

            // combine -> h1 into h1buf[(t+1)&1]; last step -> hlast fp32
            {
                float2 gi = *(const float2*)&lds_g[prow*GC_ +      phc];
                float2 gf = *(const float2*)&lds_g[prow*GC_ + 32 + phc];
                float2 gg = *(const float2*)&lds_g[prow*GC_ + 64 + phc];
                float2 go = *(const float2*)&lds_g[prow*GC_ + 96 + phc];
                c0 = sigf(gf.x+bias[2])*c0 + sigf(gi.x+bias[0])*tanh_f(gg.x+bias[4]);
                c1 = sigf(gf.y+bias[3])*c1 + sigf(gi.y+bias[1])*tanh_f(gg.y+bias[5]);
                float h0v = sigf(go.x+bias[6])*tanh_f(c0);
                float h1v = sigf(go.y+bias[7])*tanh_f(c1);
                u32 pack = (u32)f2b(h0v) | ((u32)f2b(h1v)<<16);
                __hip_atomic_store((u32*)(h1buf + ((size_t)((t+1)&1)*B_ + gb + prow)*H_ + n0 + phc),
                                   pack, __ATOMIC_RELAXED, __HIP_MEMORY_SCOPE_AGENT);
                if (t == T_-1) {
                    hlast[(size_t)(gb+prow)*H_ + n0 + phc    ] = h0v;
                    hlast[(size_t)(gb+prow)*H_ + n0 + phc + 1] = h1v;
                }
            }
            __syncthreads();
            if (tid == 0)
                __hip_atomic_store(&f1[chunk], (u32)(t+1), __ATOMIC_RELEASE, __HIP_MEMORY_SCOPE_AGENT);
        }
    }
}

// ---------------- output head ----------------
__global__ void k_out(const float* __restrict__ hlast, const float* __restrict__ Wout,
                      const float* __restrict__ bout, float* __restrict__ y)
{
    int b = blockIdx.x;
    int w = threadIdx.x>>6, lane = threadIdx.x&63;
    const float* hp = hlast + (size_t)b*H_;
    #pragma unroll
    for (int oo=0; oo<4; ++oo) {
        int o = w*4 + oo;
        const float* wp = Wout + (size_t)o*H_;
        float p = 0.f;
        for (int k=lane; k<H_; k+=64) p += hp[k]*wp[k];
        #pragma unroll
        for (int off=32; off; off>>=1) p += __shfl_down(p, off);
        if (lane==0) y[b*16 + o] = p + bout[o];
    }
}

// ---------------- workspace layout (total ~1.1MB) ----------------
static constexpr size_t OFF_RING = 0;
static constexpr size_t OFF_H1   = OFF_RING + (size_t)R_*B_*H_*2;  // 512KB
static constexpr size_t OFF_HL   = OFF_H1   + (size_t)2*B_*H_*2;   // 256KB
static constexpr size_t OFF_FLG  = OFF_HL   + (size_t)B_*H_*4;     // 256KB

extern "C" void kernel_launch(void* const* d_in, const int* in_sizes, int n_in,
                              void* d_out, int out_size, void* d_ws, size_t ws_size,
                              hipStream_t stream)
{
    (void)in_sizes; (void)n_in; (void)out_size; (void)ws_size;
    const float* x    = (const float*)d_in[0];
    const float* cond = (const float*)d_in[1];
    const float* Wc   = (const float*)d_in[2];
    const float* bc   = (const float*)d_in[3];
    const float* Wi   = (const float*)d_in[4];
    const float* bi   = (const float*)d_in[5];
    const float* Wih0 = (const float*)d_in[6];
    const float* Whh0 = (const float*)d_in[7];
    const float* bih0 = (const float*)d_in[8];
    const float* bhh0 = (const float*)d_in[9];
    const float* Wih1 = (const float*)d_in[10];
    const float* Whh1 = (const float*)d_in[11];
    const float* bih1 = (const float*)d_in[12];
    const float* bhh1 = (const float*)d_in[13];
    const float* Wout = (const float*)d_in[14];
    const float* bout = (const float*)d_in[15];
    float* y = (float*)d_out;
    char* ws = (char*)d_ws;

    u16* ring  = (u16*)(ws + OFF_RING);
    u16* h1b   = (u16*)(ws + OFF_H1);
    float* hl  = (float*)(ws + OFF_HL);
    u32* flg   = (u32*)(ws + OFF_FLG);

    k_prep<<<B_, 512, 0, stream>>>(cond, Wc, bc, Wi, bi, ring, h1b, flg);

    k_fused<<<2*NBH_*NG_, 256, 0, stream>>>(x, Wih0, Whh0, Wih1, Whh1,
                                            bih0, bhh0, bih1, bhh1,
                                            ring, h1b, flg, hl);

    k_out<<<B_, 256, 0, stream>>>(hl, Wout, bout, y);
}